// Round 1
// baseline (356.090 us; speedup 1.0000x reference)
//
#include <hip/hip_runtime.h>
#include <hip/hip_bf16.h>

typedef float f32x4 __attribute__((ext_vector_type(4)));
typedef __bf16 bf16x8 __attribute__((ext_vector_type(8)));
typedef __bf16 bf16x4 __attribute__((ext_vector_type(4)));

#define DM 1024
#define SL 2048
#define NHEAD 16

static __device__ __forceinline__ f32x4 mfma16(bf16x8 a, bf16x8 b, f32x4 c) {
    return __builtin_amdgcn_mfma_f32_16x16x32_bf16(a, b, c, 0, 0, 0);
}

// ---------------- transpose + cast: W [K=1024][N=1024] f32 -> Wt [N][K] bf16
__global__ __launch_bounds__(256) void wt_kernel(const float* __restrict__ W,
                                                 __bf16* __restrict__ Wt) {
    __shared__ float tle[32][33];
    const int tx = threadIdx.x, ty = threadIdx.y;
    const int n0 = blockIdx.x * 32, k0 = blockIdx.y * 32;
#pragma unroll
    for (int i = 0; i < 4; ++i) {
        int r = ty + 8 * i;
        tle[r][tx] = W[(size_t)(k0 + r) * DM + (n0 + tx)];
    }
    __syncthreads();
#pragma unroll
    for (int i = 0; i < 4; ++i) {
        int r = ty + 8 * i;
        Wt[(size_t)(n0 + r) * DM + (k0 + tx)] = (__bf16)tle[tx][r];
    }
}

// ---------------- shared GEMM body: Y = X(f32)[4096xK] @ Wt(bf16,[N][K])^T + bias
// mode 0: bf16 out scaled by oscale; mode 1: V stored transposed [b,h,d,s] bf16;
// mode 2: f32 out + residual
static __device__ __forceinline__ void gemm_body(
    const float* __restrict__ X, const __bf16* __restrict__ Wt,
    const float* __restrict__ bias, const float* __restrict__ resid,
    __bf16* __restrict__ Yb, float* __restrict__ Yf,
    int mode, float oscale, int r0, int c0)
{
    __shared__ __bf16 As[128][40];   // +8 pad: 2-way-conflict-free b128 reads
    __shared__ __bf16 Bs[128][40];
    const int t = threadIdx.x;
    const int w = t >> 6, lane = t & 63;
    const int l15 = lane & 15, lhi = lane >> 4;
    const int wr = w >> 1, wc = w & 1;
    const f32x4 fzero = {0.f, 0.f, 0.f, 0.f};
    f32x4 acc[4][4];
#pragma unroll
    for (int m = 0; m < 4; ++m)
#pragma unroll
        for (int n = 0; n < 4; ++n) acc[m][n] = fzero;

    for (int kt = 0; kt < DM; kt += 32) {
        __syncthreads();
        // stage A: 128x32 f32 -> bf16
#pragma unroll
        for (int i = 0; i < 4; ++i) {
            int c = t + i * 256;
            int row = c >> 3, col = (c & 7) << 2;
            float4 vv = *reinterpret_cast<const float4*>(&X[(size_t)(r0 + row) * DM + kt + col]);
            bf16x4 bv4;
            bv4[0] = (__bf16)vv.x; bv4[1] = (__bf16)vv.y;
            bv4[2] = (__bf16)vv.z; bv4[3] = (__bf16)vv.w;
            *reinterpret_cast<bf16x4*>(&As[row][col]) = bv4;
        }
        // stage B: 128 rows (output cols) x 32 k, already bf16
#pragma unroll
        for (int i = 0; i < 2; ++i) {
            int c = t + i * 256;
            int row = c >> 2, col = (c & 3) << 3;
            *reinterpret_cast<bf16x8*>(&Bs[row][col]) =
                *reinterpret_cast<const bf16x8*>(&Wt[(size_t)(c0 + row) * DM + kt + col]);
        }
        __syncthreads();
        bf16x8 af[4], bfrag[4];
#pragma unroll
        for (int m = 0; m < 4; ++m)
            af[m] = *reinterpret_cast<const bf16x8*>(&As[wr * 64 + m * 16 + l15][lhi * 8]);
#pragma unroll
        for (int n = 0; n < 4; ++n)
            bfrag[n] = *reinterpret_cast<const bf16x8*>(&Bs[wc * 64 + n * 16 + l15][lhi * 8]);
#pragma unroll
        for (int m = 0; m < 4; ++m)
#pragma unroll
            for (int n = 0; n < 4; ++n)
                acc[m][n] = mfma16(af[m], bfrag[n], acc[m][n]);
    }
#pragma unroll
    for (int m = 0; m < 4; ++m)
#pragma unroll
        for (int n = 0; n < 4; ++n)
#pragma unroll
            for (int r = 0; r < 4; ++r) {
                int grow = r0 + wr * 64 + m * 16 + lhi * 4 + r;
                int gcol = c0 + wc * 64 + n * 16 + l15;
                float val = acc[m][n][r] + bias[gcol];
                if (mode == 0) {
                    Yb[(size_t)grow * DM + gcol] = (__bf16)(val * oscale);
                } else if (mode == 1) {
                    int bb = grow >> 11, ss = grow & (SL - 1);
                    int hh = gcol >> 6, dd = gcol & 63;
                    Yb[(((size_t)(bb * NHEAD + hh)) * 64 + dd) * SL + ss] = (__bf16)val;
                } else {
                    size_t idx = (size_t)grow * DM + gcol;
                    Yf[idx] = val + resid[idx];
                }
            }
}

__global__ __launch_bounds__(256) void qkv_kernel(
    const float* __restrict__ q, const float* __restrict__ k, const float* __restrict__ v,
    const __bf16* __restrict__ WtQ, const __bf16* __restrict__ WtK, const __bf16* __restrict__ WtV,
    const float* __restrict__ bq, const float* __restrict__ bk, const float* __restrict__ bv,
    __bf16* __restrict__ Qp, __bf16* __restrict__ Kp, __bf16* __restrict__ Vt)
{
    const int z = blockIdx.z;
    const float* X = (z == 0) ? q : (z == 1) ? k : v;
    const __bf16* Wt = (z == 0) ? WtQ : (z == 1) ? WtK : WtV;
    const float* bias = (z == 0) ? bq : (z == 1) ? bk : bv;
    __bf16* Yb = (z == 0) ? Qp : (z == 1) ? Kp : Vt;
    int mode = (z == 2) ? 1 : 0;
    float oscale = (z == 0) ? 0.125f : 1.0f;  // fold 1/sqrt(D_K) into Q
    gemm_body(X, Wt, bias, nullptr, Yb, nullptr, mode, oscale,
              blockIdx.y * 128, blockIdx.x * 128);
}

__global__ __launch_bounds__(256) void oproj_kernel(
    const float* __restrict__ Cx, const __bf16* __restrict__ WtO,
    const float* __restrict__ bo, const float* __restrict__ resid,
    float* __restrict__ pre)
{
    gemm_body(Cx, WtO, bo, resid, nullptr, pre, 2, 1.0f,
              blockIdx.y * 128, blockIdx.x * 128);
}

// ---------------- flash attention: 1 wave = 16 q rows, 64-key tiles
__global__ __launch_bounds__(256) void attn_kernel(
    const __bf16* __restrict__ Qp, const __bf16* __restrict__ Kp,
    const __bf16* __restrict__ Vt, float* __restrict__ Cx)
{
    __shared__ __bf16 Pl[4][16][72];   // per-wave P tile, stride 72 breaks bank conflicts
    const int t = threadIdx.x;
    const int w = t >> 6, lane = t & 63;
    const int l15 = lane & 15, lhi = lane >> 4;
    const int bh = blockIdx.y, b = bh >> 4, h = bh & 15;
    const int q0 = blockIdx.x * 64 + w * 16;
    const size_t tokQ = (size_t)b * SL + q0;

    bf16x8 aq0 = *reinterpret_cast<const bf16x8*>(&Qp[(tokQ + l15) * DM + h * 64 + lhi * 8]);
    bf16x8 aq1 = *reinterpret_cast<const bf16x8*>(&Qp[(tokQ + l15) * DM + h * 64 + 32 + lhi * 8]);

    const f32x4 fzero = {0.f, 0.f, 0.f, 0.f};
    float m_run[4], l_run[4];
    f32x4 o_acc[4];
#pragma unroll
    for (int r = 0; r < 4; ++r) { m_run[r] = -1e30f; l_run[r] = 0.f; }
#pragma unroll
    for (int vt = 0; vt < 4; ++vt) o_acc[vt] = fzero;

    const size_t kbase = (size_t)b * SL;
    const size_t vrow0 = (size_t)(b * NHEAD + h) * 64;

    for (int kt = 0; kt < SL; kt += 64) {
        f32x4 sa[4];
#pragma unroll
        for (int nt = 0; nt < 4; ++nt) {
            const size_t kr = (kbase + kt + nt * 16 + l15) * DM + h * 64 + lhi * 8;
            bf16x8 kb0 = *reinterpret_cast<const bf16x8*>(&Kp[kr]);
            bf16x8 kb1 = *reinterpret_cast<const bf16x8*>(&Kp[kr + 32]);
            f32x4 a = fzero;
            a = mfma16(aq0, kb0, a);
            a = mfma16(aq1, kb1, a);
            sa[nt] = a;
        }
        float nm[4], sc[4], rs[4];
#pragma unroll
        for (int r = 0; r < 4; ++r) {
            float tm = fmaxf(fmaxf(sa[0][r], sa[1][r]), fmaxf(sa[2][r], sa[3][r]));
            tm = fmaxf(tm, __shfl_xor(tm, 1));
            tm = fmaxf(tm, __shfl_xor(tm, 2));
            tm = fmaxf(tm, __shfl_xor(tm, 4));
            tm = fmaxf(tm, __shfl_xor(tm, 8));
            float nmr = fmaxf(m_run[r], tm);
            sc[r] = __expf(m_run[r] - nmr);
            m_run[r] = nmr;
            nm[r] = nmr;
            rs[r] = 0.f;
        }
#pragma unroll
        for (int nt = 0; nt < 4; ++nt)
#pragma unroll
            for (int r = 0; r < 4; ++r) {
                float p = __expf(sa[nt][r] - nm[r]);
                sa[nt][r] = p;
                rs[r] += p;
            }
#pragma unroll
        for (int r = 0; r < 4; ++r) {
            float rsum = rs[r];
            rsum += __shfl_xor(rsum, 1);
            rsum += __shfl_xor(rsum, 2);
            rsum += __shfl_xor(rsum, 4);
            rsum += __shfl_xor(rsum, 8);
            l_run[r] = l_run[r] * sc[r] + rsum;
        }
#pragma unroll
        for (int vt = 0; vt < 4; ++vt)
#pragma unroll
            for (int r = 0; r < 4; ++r)
                o_acc[vt][r] *= sc[r];
        // P (C-layout) -> LDS -> A-fragment layout
#pragma unroll
        for (int nt = 0; nt < 4; ++nt)
#pragma unroll
            for (int r = 0; r < 4; ++r)
                Pl[w][lhi * 4 + r][nt * 16 + l15] = (__bf16)sa[nt][r];
#pragma unroll
        for (int kb = 0; kb < 2; ++kb) {
            bf16x8 ap = *reinterpret_cast<const bf16x8*>(&Pl[w][l15][kb * 32 + lhi * 8]);
#pragma unroll
            for (int vt = 0; vt < 4; ++vt) {
                bf16x8 bv = *reinterpret_cast<const bf16x8*>(
                    &Vt[(vrow0 + vt * 16 + l15) * SL + kt + kb * 32 + lhi * 8]);
                o_acc[vt] = mfma16(ap, bv, o_acc[vt]);
            }
        }
    }
#pragma unroll
    for (int vt = 0; vt < 4; ++vt)
#pragma unroll
        for (int r = 0; r < 4; ++r) {
            float val = o_acc[vt][r] / l_run[r];
            Cx[(tokQ + lhi * 4 + r) * DM + h * 64 + vt * 16 + l15] = val;
        }
}

// ---------------- LayerNorm over rows of 1024
__global__ __launch_bounds__(256) void ln_kernel(
    const float* __restrict__ X, const float* __restrict__ gamma,
    const float* __restrict__ beta, float* __restrict__ out)
{
    const int row = blockIdx.x, t = threadIdx.x;
    float4 v = *reinterpret_cast<const float4*>(&X[(size_t)row * DM + t * 4]);
    float s = v.x + v.y + v.z + v.w;
    float s2 = v.x * v.x + v.y * v.y + v.z * v.z + v.w * v.w;
#pragma unroll
    for (int off = 1; off < 64; off <<= 1) {
        s += __shfl_xor(s, off);
        s2 += __shfl_xor(s2, off);
    }
    __shared__ float rs[4], rs2[4];
    const int w = t >> 6;
    if ((t & 63) == 0) { rs[w] = s; rs2[w] = s2; }
    __syncthreads();
    s = rs[0] + rs[1] + rs[2] + rs[3];
    s2 = rs2[0] + rs2[1] + rs2[2] + rs2[3];
    float mean = s * (1.f / DM);
    float var = s2 * (1.f / DM) - mean * mean;
    float rstd = rsqrtf(var + 1e-5f);
    int c = t * 4;
    float4 o;
    o.x = (v.x - mean) * rstd * gamma[c + 0] + beta[c + 0];
    o.y = (v.y - mean) * rstd * gamma[c + 1] + beta[c + 1];
    o.z = (v.z - mean) * rstd * gamma[c + 2] + beta[c + 2];
    o.w = (v.w - mean) * rstd * gamma[c + 3] + beta[c + 3];
    *reinterpret_cast<float4*>(&out[(size_t)row * DM + c]) = o;
}

extern "C" void kernel_launch(void* const* d_in, const int* in_sizes, int n_in,
                              void* d_out, int out_size, void* d_ws, size_t ws_size,
                              hipStream_t stream) {
    (void)in_sizes; (void)n_in; (void)out_size; (void)ws_size;
    const float* q   = (const float*)d_in[0];
    const float* k   = (const float*)d_in[1];
    const float* v   = (const float*)d_in[2];
    const float* Wq  = (const float*)d_in[3];
    const float* bq  = (const float*)d_in[4];
    const float* Wk  = (const float*)d_in[5];
    const float* bk  = (const float*)d_in[6];
    const float* Wv  = (const float*)d_in[7];
    const float* bv  = (const float*)d_in[8];
    const float* Wo  = (const float*)d_in[9];
    const float* bo  = (const float*)d_in[10];
    const float* lng = (const float*)d_in[11];
    const float* lnb = (const float*)d_in[12];

    char* ws = (char*)d_ws;
    const size_t MB = (size_t)1 << 20;
    __bf16* WtQ = (__bf16*)(ws + 0 * MB);
    __bf16* WtK = (__bf16*)(ws + 2 * MB);
    __bf16* WtV = (__bf16*)(ws + 4 * MB);
    __bf16* WtO = (__bf16*)(ws + 6 * MB);
    __bf16* Qp  = (__bf16*)(ws + 8 * MB);    // [4096][1024] bf16, pre-scaled by 1/8
    __bf16* Kp  = (__bf16*)(ws + 16 * MB);   // [4096][1024] bf16
    __bf16* Vt  = (__bf16*)(ws + 24 * MB);   // [b][h][64][2048] bf16 (V transposed)
    float*  Cx  = (float*)(ws + 32 * MB);    // ctx f32 [4096][1024]
    float*  pre = (float*)(ws + 48 * MB);    // pre-LN f32 [4096][1024]
    // total ws use: 64 MB

    dim3 tb(32, 8);
    wt_kernel<<<dim3(32, 32), tb, 0, stream>>>(Wq, WtQ);
    wt_kernel<<<dim3(32, 32), tb, 0, stream>>>(Wk, WtK);
    wt_kernel<<<dim3(32, 32), tb, 0, stream>>>(Wv, WtV);
    wt_kernel<<<dim3(32, 32), tb, 0, stream>>>(Wo, WtO);

    qkv_kernel<<<dim3(8, 32, 3), 256, 0, stream>>>(q, k, v, WtQ, WtK, WtV,
                                                   bq, bk, bv, Qp, Kp, Vt);
    attn_kernel<<<dim3(32, 32), 256, 0, stream>>>(Qp, Kp, Vt, Cx);
    oproj_kernel<<<dim3(8, 32), 256, 0, stream>>>(Cx, WtO, bo, q, pre);
    ln_kernel<<<4096, 256, 0, stream>>>(pre, lng, lnb, (float*)d_out);
}

// Round 2
// 353.603 us; speedup vs baseline: 1.0070x; 1.0070x over previous
//
#include <hip/hip_runtime.h>
#include <hip/hip_bf16.h>

typedef float f32x4 __attribute__((ext_vector_type(4)));
typedef __bf16 bf16x8 __attribute__((ext_vector_type(8)));
typedef __bf16 bf16x4 __attribute__((ext_vector_type(4)));

#define DM 1024
#define SL 2048
#define NHEAD 16

static __device__ __forceinline__ f32x4 mfma16(bf16x8 a, bf16x8 b, f32x4 c) {
    return __builtin_amdgcn_mfma_f32_16x16x32_bf16(a, b, c, 0, 0, 0);
}

// ---------------- transpose + cast: W [K=1024][N=1024] f32 -> Wt [N][K] bf16
__global__ __launch_bounds__(256) void wt_kernel(const float* __restrict__ W,
                                                 __bf16* __restrict__ Wt) {
    __shared__ float tle[32][33];
    const int tx = threadIdx.x, ty = threadIdx.y;
    const int n0 = blockIdx.x * 32, k0 = blockIdx.y * 32;
#pragma unroll
    for (int i = 0; i < 4; ++i) {
        int r = ty + 8 * i;
        tle[r][tx] = W[(size_t)(k0 + r) * DM + (n0 + tx)];
    }
    __syncthreads();
#pragma unroll
    for (int i = 0; i < 4; ++i) {
        int r = ty + 8 * i;
        Wt[(size_t)(n0 + r) * DM + (k0 + tx)] = (__bf16)tle[tx][r];
    }
}

// ---------------- shared GEMM body: Y = X(f32)[4096xK] @ Wt(bf16,[N][K])^T + bias
// mode 0: bf16 out scaled by oscale; mode 1: V stored transposed [b,h,d,s] bf16;
// mode 2: f32 out + residual
static __device__ __forceinline__ void gemm_body(
    const float* __restrict__ X, const __bf16* __restrict__ Wt,
    const float* __restrict__ bias, const float* __restrict__ resid,
    __bf16* __restrict__ Yb, float* __restrict__ Yf,
    int mode, float oscale, int r0, int c0)
{
    __shared__ __bf16 As[128][40];   // +8 pad: 2-way-conflict-free b128 reads
    __shared__ __bf16 Bs[128][40];
    const int t = threadIdx.x;
    const int w = t >> 6, lane = t & 63;
    const int l15 = lane & 15, lhi = lane >> 4;
    const int wr = w >> 1, wc = w & 1;
    const f32x4 fzero = {0.f, 0.f, 0.f, 0.f};
    f32x4 acc[4][4];
#pragma unroll
    for (int m = 0; m < 4; ++m)
#pragma unroll
        for (int n = 0; n < 4; ++n) acc[m][n] = fzero;

    for (int kt = 0; kt < DM; kt += 32) {
        __syncthreads();
        // stage A: 128x32 f32 -> bf16
#pragma unroll
        for (int i = 0; i < 4; ++i) {
            int c = t + i * 256;
            int row = c >> 3, col = (c & 7) << 2;
            float4 vv = *reinterpret_cast<const float4*>(&X[(size_t)(r0 + row) * DM + kt + col]);
            bf16x4 bv4;
            bv4[0] = (__bf16)vv.x; bv4[1] = (__bf16)vv.y;
            bv4[2] = (__bf16)vv.z; bv4[3] = (__bf16)vv.w;
            *reinterpret_cast<bf16x4*>(&As[row][col]) = bv4;
        }
        // stage B: 128 rows (output cols) x 32 k, already bf16
#pragma unroll
        for (int i = 0; i < 2; ++i) {
            int c = t + i * 256;
            int row = c >> 2, col = (c & 3) << 3;
            *reinterpret_cast<bf16x8*>(&Bs[row][col]) =
                *reinterpret_cast<const bf16x8*>(&Wt[(size_t)(c0 + row) * DM + kt + col]);
        }
        __syncthreads();
        bf16x8 af[4], bfrag[4];
#pragma unroll
        for (int m = 0; m < 4; ++m)
            af[m] = *reinterpret_cast<const bf16x8*>(&As[wr * 64 + m * 16 + l15][lhi * 8]);
#pragma unroll
        for (int n = 0; n < 4; ++n)
            bfrag[n] = *reinterpret_cast<const bf16x8*>(&Bs[wc * 64 + n * 16 + l15][lhi * 8]);
#pragma unroll
        for (int m = 0; m < 4; ++m)
#pragma unroll
            for (int n = 0; n < 4; ++n)
                acc[m][n] = mfma16(af[m], bfrag[n], acc[m][n]);
    }
#pragma unroll
    for (int m = 0; m < 4; ++m)
#pragma unroll
        for (int n = 0; n < 4; ++n)
#pragma unroll
            for (int r = 0; r < 4; ++r) {
                int grow = r0 + wr * 64 + m * 16 + lhi * 4 + r;
                int gcol = c0 + wc * 64 + n * 16 + l15;
                float val = acc[m][n][r] + bias[gcol];
                if (mode == 0) {
                    Yb[(size_t)grow * DM + gcol] = (__bf16)(val * oscale);
                } else if (mode == 1) {
                    int bb = grow >> 11, ss = grow & (SL - 1);
                    int hh = gcol >> 6, dd = gcol & 63;
                    Yb[(((size_t)(bb * NHEAD + hh)) * 64 + dd) * SL + ss] = (__bf16)val;
                } else {
                    size_t idx = (size_t)grow * DM + gcol;
                    Yf[idx] = val + resid[idx];
                }
            }
}

__global__ __launch_bounds__(256) void qkv_kernel(
    const float* __restrict__ q, const float* __restrict__ k, const float* __restrict__ v,
    const __bf16* __restrict__ WtQ, const __bf16* __restrict__ WtK, const __bf16* __restrict__ WtV,
    const float* __restrict__ bq, const float* __restrict__ bk, const float* __restrict__ bv,
    __bf16* __restrict__ Qp, __bf16* __restrict__ Kp, __bf16* __restrict__ Vt)
{
    const int z = blockIdx.z;
    const float* X = (z == 0) ? q : (z == 1) ? k : v;
    const __bf16* Wt = (z == 0) ? WtQ : (z == 1) ? WtK : WtV;
    const float* bias = (z == 0) ? bq : (z == 1) ? bk : bv;
    __bf16* Yb = (z == 0) ? Qp : (z == 1) ? Kp : Vt;
    int mode = (z == 2) ? 1 : 0;
    float oscale = (z == 0) ? 0.125f : 1.0f;  // fold 1/sqrt(D_K) into Q
    gemm_body(X, Wt, bias, nullptr, Yb, nullptr, mode, oscale,
              blockIdx.y * 128, blockIdx.x * 128);
}

__global__ __launch_bounds__(256) void oproj_kernel(
    const float* __restrict__ Cx, const __bf16* __restrict__ WtO,
    const float* __restrict__ bo, const float* __restrict__ resid,
    float* __restrict__ pre)
{
    gemm_body(Cx, WtO, bo, resid, nullptr, pre, 2, 1.0f,
              blockIdx.y * 128, blockIdx.x * 128);
}

// ---------------- flash attention v2: swapped QK^T, per-lane-row softmax,
// defer-max, XCD swizzle. 1 wave = 16 q rows, 64-key tiles.
__global__ __launch_bounds__(256, 4) void attn_kernel(
    const __bf16* __restrict__ Qp, const __bf16* __restrict__ Kp,
    const __bf16* __restrict__ Vt, float* __restrict__ Cx)
{
    __shared__ __bf16 Pl[4][16][72];   // per-wave P tile
    const int t = threadIdx.x;
    const int w = t >> 6, lane = t & 63;
    const int l15 = lane & 15, lhi = lane >> 4;

    // XCD swizzle: 1024 blocks, 8 XCDs -> each XCD owns 4 consecutive bh
    // (K/V working set 4 x 512KB = 2MB, fits the 4MB per-XCD L2)
    const int id = blockIdx.x;
    const int logical = (id & 7) * 128 + (id >> 3);
    const int bh = logical >> 5, qb = logical & 31;
    const int b = bh >> 4, h = bh & 15;
    const int q0 = qb * 64 + w * 16;
    const size_t tokQ = (size_t)b * SL + q0;

    // Q fragment (pre-scaled by 1/sqrt(Dk) in qkv): lane holds q-row l15, dims lhi*8..+7
    bf16x8 aq0 = *reinterpret_cast<const bf16x8*>(&Qp[(tokQ + l15) * DM + h * 64 + lhi * 8]);
    bf16x8 aq1 = *reinterpret_cast<const bf16x8*>(&Qp[(tokQ + l15) * DM + h * 64 + 32 + lhi * 8]);

    const f32x4 fzero = {0.f, 0.f, 0.f, 0.f};
    float m_run = -1e30f, l_run = 0.f;   // lane owns q-row (l15)
    f32x4 o_acc[4];
#pragma unroll
    for (int vt = 0; vt < 4; ++vt) o_acc[vt] = fzero;

    const size_t kbase = (size_t)b * SL;
    const size_t vrow0 = (size_t)(b * NHEAD + h) * 64;

    for (int kt = 0; kt < SL; kt += 64) {
        // ---- QK^T swapped: C[key][q] -> lane holds q-row=l15, keys nt*16+lhi*4+r
        f32x4 sa[4];
        __builtin_amdgcn_s_setprio(1);
#pragma unroll
        for (int nt = 0; nt < 4; ++nt) {
            const size_t kr = (kbase + kt + nt * 16 + l15) * DM + h * 64 + lhi * 8;
            bf16x8 kb0 = *reinterpret_cast<const bf16x8*>(&Kp[kr]);
            bf16x8 kb1 = *reinterpret_cast<const bf16x8*>(&Kp[kr + 32]);
            f32x4 a = fzero;
            a = mfma16(kb0, aq0, a);
            a = mfma16(kb1, aq1, a);
            sa[nt] = a;
        }
        __builtin_amdgcn_s_setprio(0);

        // ---- per-lane row softmax: 15 local max + 2 shfl
        float tm = sa[0][0];
#pragma unroll
        for (int nt = 0; nt < 4; ++nt)
#pragma unroll
            for (int r = 0; r < 4; ++r) tm = fmaxf(tm, sa[nt][r]);
        tm = fmaxf(tm, __shfl_xor(tm, 16));
        tm = fmaxf(tm, __shfl_xor(tm, 32));

        // defer-max: only rescale when a row grew by > 8 (wave-uniform branch)
        if (__any(tm > m_run + 8.f)) {
            float nm = fmaxf(m_run, tm);
            float sc = __expf(m_run - nm);
            m_run = nm;
            l_run *= sc;
            float scq[4];
#pragma unroll
            for (int r = 0; r < 4; ++r) scq[r] = __shfl(sc, lhi * 4 + r);
#pragma unroll
            for (int vt = 0; vt < 4; ++vt)
#pragma unroll
                for (int r = 0; r < 4; ++r) o_acc[vt][r] *= scq[r];
        }

        // ---- P = exp(S - m), row-sum, write P tile (bf16) to LDS
        float rs = 0.f;
#pragma unroll
        for (int nt = 0; nt < 4; ++nt) {
            bf16x4 pb;
#pragma unroll
            for (int r = 0; r < 4; ++r) {
                float p = __expf(sa[nt][r] - m_run);
                rs += p;
                pb[r] = (__bf16)p;
            }
            *reinterpret_cast<bf16x4*>(&Pl[w][l15][nt * 16 + lhi * 4]) = pb;
        }
        rs += __shfl_xor(rs, 16);
        rs += __shfl_xor(rs, 32);
        l_run += rs;

        // ---- PV: A = P tile (from LDS), B = V^T fragments
        __builtin_amdgcn_s_setprio(1);
#pragma unroll
        for (int kb = 0; kb < 2; ++kb) {
            bf16x8 ap = *reinterpret_cast<const bf16x8*>(&Pl[w][l15][kb * 32 + lhi * 8]);
#pragma unroll
            for (int vt = 0; vt < 4; ++vt) {
                bf16x8 bv = *reinterpret_cast<const bf16x8*>(
                    &Vt[(vrow0 + vt * 16 + l15) * SL + kt + kb * 32 + lhi * 8]);
                o_acc[vt] = mfma16(ap, bv, o_acc[vt]);
            }
        }
        __builtin_amdgcn_s_setprio(0);
    }

    // final normalize: l for q-row 4*lhi+r lives in lane (4*lhi+r)
    float lr[4];
#pragma unroll
    for (int r = 0; r < 4; ++r) lr[r] = __shfl(l_run, lhi * 4 + r);
#pragma unroll
    for (int vt = 0; vt < 4; ++vt)
#pragma unroll
        for (int r = 0; r < 4; ++r) {
            float val = o_acc[vt][r] / lr[r];
            Cx[(tokQ + lhi * 4 + r) * DM + h * 64 + vt * 16 + l15] = val;
        }
}

// ---------------- LayerNorm over rows of 1024
__global__ __launch_bounds__(256) void ln_kernel(
    const float* __restrict__ X, const float* __restrict__ gamma,
    const float* __restrict__ beta, float* __restrict__ out)
{
    const int row = blockIdx.x, t = threadIdx.x;
    float4 v = *reinterpret_cast<const float4*>(&X[(size_t)row * DM + t * 4]);
    float s = v.x + v.y + v.z + v.w;
    float s2 = v.x * v.x + v.y * v.y + v.z * v.z + v.w * v.w;
#pragma unroll
    for (int off = 1; off < 64; off <<= 1) {
        s += __shfl_xor(s, off);
        s2 += __shfl_xor(s2, off);
    }
    __shared__ float rs[4], rs2[4];
    const int w = t >> 6;
    if ((t & 63) == 0) { rs[w] = s; rs2[w] = s2; }
    __syncthreads();
    s = rs[0] + rs[1] + rs[2] + rs[3];
    s2 = rs2[0] + rs2[1] + rs2[2] + rs2[3];
    float mean = s * (1.f / DM);
    float var = s2 * (1.f / DM) - mean * mean;
    float rstd = rsqrtf(var + 1e-5f);
    int c = t * 4;
    float4 o;
    o.x = (v.x - mean) * rstd * gamma[c + 0] + beta[c + 0];
    o.y = (v.y - mean) * rstd * gamma[c + 1] + beta[c + 1];
    o.z = (v.z - mean) * rstd * gamma[c + 2] + beta[c + 2];
    o.w = (v.w - mean) * rstd * gamma[c + 3] + beta[c + 3];
    *reinterpret_cast<float4*>(&out[(size_t)row * DM + c]) = o;
}

extern "C" void kernel_launch(void* const* d_in, const int* in_sizes, int n_in,
                              void* d_out, int out_size, void* d_ws, size_t ws_size,
                              hipStream_t stream) {
    (void)in_sizes; (void)n_in; (void)out_size; (void)ws_size;
    const float* q   = (const float*)d_in[0];
    const float* k   = (const float*)d_in[1];
    const float* v   = (const float*)d_in[2];
    const float* Wq  = (const float*)d_in[3];
    const float* bq  = (const float*)d_in[4];
    const float* Wk  = (const float*)d_in[5];
    const float* bk  = (const float*)d_in[6];
    const float* Wv  = (const float*)d_in[7];
    const float* bv  = (const float*)d_in[8];
    const float* Wo  = (const float*)d_in[9];
    const float* bo  = (const float*)d_in[10];
    const float* lng = (const float*)d_in[11];
    const float* lnb = (const float*)d_in[12];

    char* ws = (char*)d_ws;
    const size_t MB = (size_t)1 << 20;
    __bf16* WtQ = (__bf16*)(ws + 0 * MB);
    __bf16* WtK = (__bf16*)(ws + 2 * MB);
    __bf16* WtV = (__bf16*)(ws + 4 * MB);
    __bf16* WtO = (__bf16*)(ws + 6 * MB);
    __bf16* Qp  = (__bf16*)(ws + 8 * MB);    // [4096][1024] bf16, pre-scaled by 1/8
    __bf16* Kp  = (__bf16*)(ws + 16 * MB);   // [4096][1024] bf16
    __bf16* Vt  = (__bf16*)(ws + 24 * MB);   // [b][h][64][2048] bf16 (V transposed)
    float*  Cx  = (float*)(ws + 32 * MB);    // ctx f32 [4096][1024]
    float*  pre = (float*)(ws + 48 * MB);    // pre-LN f32 [4096][1024]
    // total ws use: 64 MB

    dim3 tb(32, 8);
    wt_kernel<<<dim3(32, 32), tb, 0, stream>>>(Wq, WtQ);
    wt_kernel<<<dim3(32, 32), tb, 0, stream>>>(Wk, WtK);
    wt_kernel<<<dim3(32, 32), tb, 0, stream>>>(Wv, WtV);
    wt_kernel<<<dim3(32, 32), tb, 0, stream>>>(Wo, WtO);

    qkv_kernel<<<dim3(8, 32, 3), 256, 0, stream>>>(q, k, v, WtQ, WtK, WtV,
                                                   bq, bk, bv, Qp, Kp, Vt);
    attn_kernel<<<dim3(1024), 256, 0, stream>>>(Qp, Kp, Vt, Cx);
    oproj_kernel<<<dim3(8, 32), 256, 0, stream>>>(Cx, WtO, bo, q, pre);
    ln_kernel<<<4096, 256, 0, stream>>>(pre, lng, lnb, (float*)d_out);
}

// Round 3
// 198.216 us; speedup vs baseline: 1.7965x; 1.7839x over previous
//
#include <hip/hip_runtime.h>
#include <hip/hip_bf16.h>

typedef float f32x4 __attribute__((ext_vector_type(4)));
typedef float f32x16 __attribute__((ext_vector_type(16)));
typedef __bf16 bf16x8 __attribute__((ext_vector_type(8)));
typedef __bf16 bf16x4 __attribute__((ext_vector_type(4)));

#define DM 1024
#define SL 2048
#define NHEAD 16

static __device__ __forceinline__ f32x4 mfma16(bf16x8 a, bf16x8 b, f32x4 c) {
    return __builtin_amdgcn_mfma_f32_16x16x32_bf16(a, b, c, 0, 0, 0);
}
static __device__ __forceinline__ f32x16 mfma32(bf16x8 a, bf16x8 b, f32x16 c) {
    return __builtin_amdgcn_mfma_f32_32x32x16_bf16(a, b, c, 0, 0, 0);
}

// pack two f32 -> one u32 of 2 bf16 (lo, hi)
static __device__ __forceinline__ unsigned packbf(float lo, float hi) {
    unsigned short lu = __builtin_bit_cast(unsigned short, (__bf16)lo);
    unsigned short hu = __builtin_bit_cast(unsigned short, (__bf16)hi);
    return ((unsigned)hu << 16) | (unsigned)lu;
}

// cross-half word exchange: A' = (src hi=0)'s word at t=2k+hi ; B' = (src hi=1)'s
static __device__ __forceinline__ void half_swap(unsigned wa, unsigned wb, int hi,
                                                 unsigned &A, unsigned &B) {
    unsigned pa = (unsigned)__shfl_xor((int)wa, 32);
    unsigned pb = (unsigned)__shfl_xor((int)wb, 32);
    A = hi ? pb : wa;
    B = hi ? wb : pa;
}

// ---------------- transpose + cast: W [K=1024][N=1024] f32 -> Wt [N][K] bf16
__global__ __launch_bounds__(256) void wt_kernel(const float* __restrict__ W,
                                                 __bf16* __restrict__ Wt) {
    __shared__ float tle[32][33];
    const int tx = threadIdx.x, ty = threadIdx.y;
    const int n0 = blockIdx.x * 32, k0 = blockIdx.y * 32;
#pragma unroll
    for (int i = 0; i < 4; ++i) {
        int r = ty + 8 * i;
        tle[r][tx] = W[(size_t)(k0 + r) * DM + (n0 + tx)];
    }
    __syncthreads();
#pragma unroll
    for (int i = 0; i < 4; ++i) {
        int r = ty + 8 * i;
        Wt[(size_t)(n0 + r) * DM + (k0 + tx)] = (__bf16)tle[tx][r];
    }
}

// ---------------- shared GEMM body (unchanged from round 1)
static __device__ __forceinline__ void gemm_body(
    const float* __restrict__ X, const __bf16* __restrict__ Wt,
    const float* __restrict__ bias, const float* __restrict__ resid,
    __bf16* __restrict__ Yb, float* __restrict__ Yf,
    int mode, float oscale, int r0, int c0)
{
    __shared__ __bf16 As[128][40];
    __shared__ __bf16 Bs[128][40];
    const int t = threadIdx.x;
    const int w = t >> 6, lane = t & 63;
    const int l15 = lane & 15, lhi = lane >> 4;
    const int wr = w >> 1, wc = w & 1;
    const f32x4 fzero = {0.f, 0.f, 0.f, 0.f};
    f32x4 acc[4][4];
#pragma unroll
    for (int m = 0; m < 4; ++m)
#pragma unroll
        for (int n = 0; n < 4; ++n) acc[m][n] = fzero;

    for (int kt = 0; kt < DM; kt += 32) {
        __syncthreads();
#pragma unroll
        for (int i = 0; i < 4; ++i) {
            int c = t + i * 256;
            int row = c >> 3, col = (c & 7) << 2;
            float4 vv = *reinterpret_cast<const float4*>(&X[(size_t)(r0 + row) * DM + kt + col]);
            bf16x4 bv4;
            bv4[0] = (__bf16)vv.x; bv4[1] = (__bf16)vv.y;
            bv4[2] = (__bf16)vv.z; bv4[3] = (__bf16)vv.w;
            *reinterpret_cast<bf16x4*>(&As[row][col]) = bv4;
        }
#pragma unroll
        for (int i = 0; i < 2; ++i) {
            int c = t + i * 256;
            int row = c >> 2, col = (c & 3) << 3;
            *reinterpret_cast<bf16x8*>(&Bs[row][col]) =
                *reinterpret_cast<const bf16x8*>(&Wt[(size_t)(c0 + row) * DM + kt + col]);
        }
        __syncthreads();
        bf16x8 af[4], bfrag[4];
#pragma unroll
        for (int m = 0; m < 4; ++m)
            af[m] = *reinterpret_cast<const bf16x8*>(&As[wr * 64 + m * 16 + l15][lhi * 8]);
#pragma unroll
        for (int n = 0; n < 4; ++n)
            bfrag[n] = *reinterpret_cast<const bf16x8*>(&Bs[wc * 64 + n * 16 + l15][lhi * 8]);
#pragma unroll
        for (int m = 0; m < 4; ++m)
#pragma unroll
            for (int n = 0; n < 4; ++n)
                acc[m][n] = mfma16(af[m], bfrag[n], acc[m][n]);
    }
#pragma unroll
    for (int m = 0; m < 4; ++m)
#pragma unroll
        for (int n = 0; n < 4; ++n)
#pragma unroll
            for (int r = 0; r < 4; ++r) {
                int grow = r0 + wr * 64 + m * 16 + lhi * 4 + r;
                int gcol = c0 + wc * 64 + n * 16 + l15;
                float val = acc[m][n][r] + bias[gcol];
                if (mode == 0) {
                    Yb[(size_t)grow * DM + gcol] = (__bf16)(val * oscale);
                } else if (mode == 1) {
                    int bb = grow >> 11, ss = grow & (SL - 1);
                    int hh = gcol >> 6, dd = gcol & 63;
                    Yb[(((size_t)(bb * NHEAD + hh)) * 64 + dd) * SL + ss] = (__bf16)val;
                } else {
                    size_t idx = (size_t)grow * DM + gcol;
                    Yf[idx] = val + resid[idx];
                }
            }
}

__global__ __launch_bounds__(256) void qkv_kernel(
    const float* __restrict__ q, const float* __restrict__ k, const float* __restrict__ v,
    const __bf16* __restrict__ WtQ, const __bf16* __restrict__ WtK, const __bf16* __restrict__ WtV,
    const float* __restrict__ bq, const float* __restrict__ bk, const float* __restrict__ bv,
    __bf16* __restrict__ Qp, __bf16* __restrict__ Kp, __bf16* __restrict__ Vt)
{
    const int z = blockIdx.z;
    const float* X = (z == 0) ? q : (z == 1) ? k : v;
    const __bf16* Wt = (z == 0) ? WtQ : (z == 1) ? WtK : WtV;
    const float* bias = (z == 0) ? bq : (z == 1) ? bk : bv;
    __bf16* Yb = (z == 0) ? Qp : (z == 1) ? Kp : Vt;
    int mode = (z == 2) ? 1 : 0;
    float oscale = (z == 0) ? 0.125f : 1.0f;
    gemm_body(X, Wt, bias, nullptr, Yb, nullptr, mode, oscale,
              blockIdx.y * 128, blockIdx.x * 128);
}

__global__ __launch_bounds__(256) void oproj_kernel(
    const float* __restrict__ Cx, const __bf16* __restrict__ WtO,
    const float* __restrict__ bo, const float* __restrict__ resid,
    float* __restrict__ pre)
{
    gemm_body(Cx, WtO, bo, resid, nullptr, pre, 2, 1.0f,
              blockIdx.y * 128, blockIdx.x * 128);
}

// ---------------- flash attention v3: 8 waves/block, 32 q-rows/wave,
// 32x32x16 MFMA, LDS-shared swizzled K/V tiles, in-register softmax.
__global__ __launch_bounds__(512, 2) void attn_kernel(
    const __bf16* __restrict__ Qp, const __bf16* __restrict__ Kp,
    const __bf16* __restrict__ Vt, float* __restrict__ Cx)
{
    __shared__ __attribute__((aligned(16))) __bf16 Kl[4096];  // [64 key][64 d], XOR-swz
    __shared__ __attribute__((aligned(16))) __bf16 Vl[4096];  // [64 d][64 key], XOR-swz
    const int t = threadIdx.x;
    const int w = t >> 6, lane = t & 63;
    const int l31 = lane & 31, hi = lane >> 5;

    // XCD swizzle: XCD x owns 4 consecutive bh (K/V 2MB -> L2-resident)
    const int id = blockIdx.x;
    const int logical = (id & 7) * 32 + (id >> 3);
    const int bh = logical >> 3, qs = logical & 7;
    const int b = bh >> 4, h = bh & 15;
    const size_t tokQ = (size_t)b * SL + qs * 256 + w * 32;
    const size_t kbase = (size_t)b * SL;
    const size_t vrow0 = (size_t)bh * 64;

    // staging coords: 512 threads, 1 bf16x8 each for K and V
    const int srow = t >> 3, scol = (t & 7) << 3;
    const __bf16* gK = &Kp[(kbase + srow) * DM + h * 64 + scol];
    const __bf16* gV = &Vt[(vrow0 + srow) * SL + scol];
    const int sidx = ((srow * 128 + scol * 2) ^ ((srow & 7) << 4)) >> 1;

    // Q B-fragments: col=l31 -> q-row, k=d=16*ks+8*hi+j (Q pre-scaled by 1/8)
    bf16x8 bq[4];
#pragma unroll
    for (int ks = 0; ks < 4; ++ks)
        bq[ks] = *reinterpret_cast<const bf16x8*>(
            &Qp[(tokQ + l31) * DM + h * 64 + ks * 16 + hi * 8]);

    f32x16 o0, o1;
#pragma unroll
    for (int r = 0; r < 16; ++r) { o0[r] = 0.f; o1[r] = 0.f; }
    float m_run = -1e30f, l_run = 0.f;

    const int swz = (l31 & 7) << 4;

    for (int kt = 0; kt < SL; kt += 64) {
        __syncthreads();
        bf16x8 kv = *reinterpret_cast<const bf16x8*>(gK + (size_t)kt * DM);
        bf16x8 vv = *reinterpret_cast<const bf16x8*>(gV + kt);
        *reinterpret_cast<bf16x8*>(&Kl[sidx]) = kv;
        *reinterpret_cast<bf16x8*>(&Vl[sidx]) = vv;
        __syncthreads();

        // ---- QK^T (swapped): C[key][q], keys 0..31 in c0, 32..63 in c1
        f32x16 c0, c1;
#pragma unroll
        for (int r = 0; r < 16; ++r) { c0[r] = 0.f; c1[r] = 0.f; }
        __builtin_amdgcn_s_setprio(1);
#pragma unroll
        for (int ks = 0; ks < 4; ++ks) {
            int off = ks * 32 + hi * 16;
            bf16x8 ak0 = *reinterpret_cast<const bf16x8*>(&Kl[((l31 * 128 + off) ^ swz) >> 1]);
            bf16x8 ak1 = *reinterpret_cast<const bf16x8*>(&Kl[(((32 + l31) * 128 + off) ^ swz) >> 1]);
            c0 = mfma32(ak0, bq[ks], c0);
            c1 = mfma32(ak1, bq[ks], c1);
        }
        __builtin_amdgcn_s_setprio(0);

        // ---- in-register softmax: lane owns q=l31, 32 of 64 keys (pair lane^32)
        float tm = c0[0];
#pragma unroll
        for (int r = 1; r < 16; ++r) tm = fmaxf(tm, c0[r]);
#pragma unroll
        for (int r = 0; r < 16; ++r) tm = fmaxf(tm, c1[r]);
        tm = fmaxf(tm, __shfl_xor(tm, 32));

        if (__any(tm > m_run + 8.f)) {   // defer-max
            float nm = fmaxf(m_run, tm);
            float sc = __expf(m_run - nm);
            m_run = nm;
            l_run *= sc;
#pragma unroll
            for (int r = 0; r < 16; ++r) {
                float sq = __shfl(sc, (r & 3) + 8 * (r >> 2) + 4 * hi);
                o0[r] *= sq; o1[r] *= sq;
            }
        }

        float rs = 0.f;
#pragma unroll
        for (int r = 0; r < 16; ++r) { c0[r] = __expf(c0[r] - m_run); rs += c0[r]; }
#pragma unroll
        for (int r = 0; r < 16; ++r) { c1[r] = __expf(c1[r] - m_run); rs += c1[r]; }
        rs += __shfl_xor(rs, 32);
        l_run += rs;

        // ---- pack P -> bf16 words: wd[m][2*t+p] = keys (32m + 8t + 4hi + 2p, +1)
        unsigned wd0[8], wd1[8];
#pragma unroll
        for (int tt = 0; tt < 4; ++tt)
#pragma unroll
            for (int p = 0; p < 2; ++p) {
                wd0[tt * 2 + p] = packbf(c0[4 * tt + 2 * p], c0[4 * tt + 2 * p + 1]);
                wd1[tt * 2 + p] = packbf(c1[4 * tt + 2 * p], c1[4 * tt + 2 * p + 1]);
            }
        // ---- redistribute to PV A-fragments: a[s][j] = P[q=l31][16s+8hi+j]
        unsigned ua[4][4];
#pragma unroll
        for (int s = 0; s < 4; ++s) {
            int tA = (s & 1) * 2;           // t pair {tA, tA+1} from m-tile s>>1
#pragma unroll
            for (int p = 0; p < 2; ++p) {
                unsigned A, B;
                if (s < 2) half_swap(wd0[tA * 2 + p], wd0[(tA + 1) * 2 + p], hi, A, B);
                else       half_swap(wd1[tA * 2 + p], wd1[(tA + 1) * 2 + p], hi, A, B);
                ua[s][p] = A; ua[s][2 + p] = B;
            }
        }

        // ---- PV: o[n] += a[s] x V[k][d], V from swizzled LDS [d][key]
        __builtin_amdgcn_s_setprio(1);
#pragma unroll
        for (int s = 0; s < 4; ++s) {
            bf16x8 as = *reinterpret_cast<const bf16x8*>(&ua[s][0]);
            bf16x8 vf0 = *reinterpret_cast<const bf16x8*>(
                &Vl[((l31 * 128 + s * 32 + hi * 16) ^ swz) >> 1]);
            bf16x8 vf1 = *reinterpret_cast<const bf16x8*>(
                &Vl[(((32 + l31) * 128 + s * 32 + hi * 16) ^ swz) >> 1]);
            o0 = mfma32(as, vf0, o0);
            o1 = mfma32(as, vf1, o1);
        }
        __builtin_amdgcn_s_setprio(0);
    }

    // ---- normalize + write: o{n}[r] = O[q=crow(r,hi)][d=32n+l31]
#pragma unroll
    for (int r = 0; r < 16; ++r) {
        int qq = (r & 3) + 8 * (r >> 2) + 4 * hi;
        float inv = 1.f / __shfl(l_run, qq);
        size_t rowi = (tokQ + qq) * DM + h * 64;
        Cx[rowi + l31]      = o0[r] * inv;
        Cx[rowi + 32 + l31] = o1[r] * inv;
    }
}

// ---------------- LayerNorm over rows of 1024
__global__ __launch_bounds__(256) void ln_kernel(
    const float* __restrict__ X, const float* __restrict__ gamma,
    const float* __restrict__ beta, float* __restrict__ out)
{
    const int row = blockIdx.x, t = threadIdx.x;
    float4 v = *reinterpret_cast<const float4*>(&X[(size_t)row * DM + t * 4]);
    float s = v.x + v.y + v.z + v.w;
    float s2 = v.x * v.x + v.y * v.y + v.z * v.z + v.w * v.w;
#pragma unroll
    for (int off = 1; off < 64; off <<= 1) {
        s += __shfl_xor(s, off);
        s2 += __shfl_xor(s2, off);
    }
    __shared__ float rs[4], rs2[4];
    const int w = t >> 6;
    if ((t & 63) == 0) { rs[w] = s; rs2[w] = s2; }
    __syncthreads();
    s = rs[0] + rs[1] + rs[2] + rs[3];
    s2 = rs2[0] + rs2[1] + rs2[2] + rs2[3];
    float mean = s * (1.f / DM);
    float var = s2 * (1.f / DM) - mean * mean;
    float rstd = rsqrtf(var + 1e-5f);
    int c = t * 4;
    float4 o;
    o.x = (v.x - mean) * rstd * gamma[c + 0] + beta[c + 0];
    o.y = (v.y - mean) * rstd * gamma[c + 1] + beta[c + 1];
    o.z = (v.z - mean) * rstd * gamma[c + 2] + beta[c + 2];
    o.w = (v.w - mean) * rstd * gamma[c + 3] + beta[c + 3];
    *reinterpret_cast<float4*>(&out[(size_t)row * DM + c]) = o;
}

extern "C" void kernel_launch(void* const* d_in, const int* in_sizes, int n_in,
                              void* d_out, int out_size, void* d_ws, size_t ws_size,
                              hipStream_t stream) {
    (void)in_sizes; (void)n_in; (void)out_size; (void)ws_size;
    const float* q   = (const float*)d_in[0];
    const float* k   = (const float*)d_in[1];
    const float* v   = (const float*)d_in[2];
    const float* Wq  = (const float*)d_in[3];
    const float* bq  = (const float*)d_in[4];
    const float* Wk  = (const float*)d_in[5];
    const float* bk  = (const float*)d_in[6];
    const float* Wv  = (const float*)d_in[7];
    const float* bv  = (const float*)d_in[8];
    const float* Wo  = (const float*)d_in[9];
    const float* bo  = (const float*)d_in[10];
    const float* lng = (const float*)d_in[11];
    const float* lnb = (const float*)d_in[12];

    char* ws = (char*)d_ws;
    const size_t MB = (size_t)1 << 20;
    __bf16* WtQ = (__bf16*)(ws + 0 * MB);
    __bf16* WtK = (__bf16*)(ws + 2 * MB);
    __bf16* WtV = (__bf16*)(ws + 4 * MB);
    __bf16* WtO = (__bf16*)(ws + 6 * MB);
    __bf16* Qp  = (__bf16*)(ws + 8 * MB);    // [4096][1024] bf16, pre-scaled by 1/8
    __bf16* Kp  = (__bf16*)(ws + 16 * MB);   // [4096][1024] bf16
    __bf16* Vt  = (__bf16*)(ws + 24 * MB);   // [b][h][64][2048] bf16 (V transposed)
    float*  Cx  = (float*)(ws + 32 * MB);    // ctx f32 [4096][1024]
    float*  pre = (float*)(ws + 48 * MB);    // pre-LN f32 [4096][1024]

    dim3 tb(32, 8);
    wt_kernel<<<dim3(32, 32), tb, 0, stream>>>(Wq, WtQ);
    wt_kernel<<<dim3(32, 32), tb, 0, stream>>>(Wk, WtK);
    wt_kernel<<<dim3(32, 32), tb, 0, stream>>>(Wv, WtV);
    wt_kernel<<<dim3(32, 32), tb, 0, stream>>>(Wo, WtO);

    qkv_kernel<<<dim3(8, 32, 3), 256, 0, stream>>>(q, k, v, WtQ, WtK, WtV,
                                                   bq, bk, bv, Qp, Kp, Vt);
    attn_kernel<<<dim3(256), 512, 0, stream>>>(Qp, Kp, Vt, Cx);
    oproj_kernel<<<dim3(8, 32), 256, 0, stream>>>(Cx, WtO, bo, q, pre);
    ln_kernel<<<4096, 256, 0, stream>>>(pre, lng, lnb, (float*)d_out);
}

// Round 4
// 173.539 us; speedup vs baseline: 2.0519x; 1.1422x over previous
//
#include <hip/hip_runtime.h>
#include <hip/hip_bf16.h>

typedef float f32x4 __attribute__((ext_vector_type(4)));
typedef float f32x16 __attribute__((ext_vector_type(16)));
typedef __bf16 bf16x8 __attribute__((ext_vector_type(8)));
typedef __bf16 bf16x4 __attribute__((ext_vector_type(4)));

#define DM 1024
#define SL 2048
#define NHEAD 16

static __device__ __forceinline__ f32x4 mfma16(bf16x8 a, bf16x8 b, f32x4 c) {
    return __builtin_amdgcn_mfma_f32_16x16x32_bf16(a, b, c, 0, 0, 0);
}
static __device__ __forceinline__ f32x16 mfma32(bf16x8 a, bf16x8 b, f32x16 c) {
    return __builtin_amdgcn_mfma_f32_32x32x16_bf16(a, b, c, 0, 0, 0);
}

// async global->LDS, 16B per lane; lds dest = wave-uniform base + lane*16
static __device__ __forceinline__ void gload16(const void* g, void* l) {
    __builtin_amdgcn_global_load_lds(
        (const __attribute__((address_space(1))) unsigned*)g,
        (__attribute__((address_space(3))) unsigned*)l, 16, 0, 0);
}

// pack two f32 -> one u32 of 2 bf16 (lo, hi)
static __device__ __forceinline__ unsigned packbf(float lo, float hi) {
    unsigned short lu = __builtin_bit_cast(unsigned short, (__bf16)lo);
    unsigned short hu = __builtin_bit_cast(unsigned short, (__bf16)hi);
    return ((unsigned)hu << 16) | (unsigned)lu;
}

static __device__ __forceinline__ void half_swap(unsigned wa, unsigned wb, int hi,
                                                 unsigned &A, unsigned &B) {
    unsigned pa = (unsigned)__shfl_xor((int)wa, 32);
    unsigned pb = (unsigned)__shfl_xor((int)wb, 32);
    A = hi ? pb : wa;
    B = hi ? wb : pa;
}

// ---------------- cast f32 -> bf16, 8 elems/thread
__global__ __launch_bounds__(256) void cast_kernel(
    const float* __restrict__ x0, const float* __restrict__ x1, const float* __restrict__ x2,
    __bf16* __restrict__ y0, __bf16* __restrict__ y1, __bf16* __restrict__ y2)
{
    const float* x = (blockIdx.y == 0) ? x0 : (blockIdx.y == 1) ? x1 : x2;
    __bf16* y = (blockIdx.y == 0) ? y0 : (blockIdx.y == 1) ? y1 : y2;
    size_t i = ((size_t)blockIdx.x * 256 + threadIdx.x) * 8;
    float4 a = *reinterpret_cast<const float4*>(&x[i]);
    float4 b = *reinterpret_cast<const float4*>(&x[i + 4]);
    bf16x8 o;
    o[0] = (__bf16)a.x; o[1] = (__bf16)a.y; o[2] = (__bf16)a.z; o[3] = (__bf16)a.w;
    o[4] = (__bf16)b.x; o[5] = (__bf16)b.y; o[6] = (__bf16)b.z; o[7] = (__bf16)b.w;
    *reinterpret_cast<bf16x8*>(&y[i]) = o;
}

// ---------------- transpose + cast all 4 weights: W [K][N] f32 -> Wt [N][K] bf16
__global__ __launch_bounds__(256) void wt4_kernel(
    const float* __restrict__ W0, const float* __restrict__ W1,
    const float* __restrict__ W2, const float* __restrict__ W3,
    __bf16* __restrict__ T0, __bf16* __restrict__ T1,
    __bf16* __restrict__ T2, __bf16* __restrict__ T3)
{
    const float* W = (blockIdx.z == 0) ? W0 : (blockIdx.z == 1) ? W1
                   : (blockIdx.z == 2) ? W2 : W3;
    __bf16* Wt = (blockIdx.z == 0) ? T0 : (blockIdx.z == 1) ? T1
               : (blockIdx.z == 2) ? T2 : T3;
    __shared__ float tle[32][33];
    const int tx = threadIdx.x, ty = threadIdx.y;
    const int n0 = blockIdx.x * 32, k0 = blockIdx.y * 32;
#pragma unroll
    for (int i = 0; i < 4; ++i) {
        int r = ty + 8 * i;
        tle[r][tx] = W[(size_t)(k0 + r) * DM + (n0 + tx)];
    }
    __syncthreads();
#pragma unroll
    for (int i = 0; i < 4; ++i) {
        int r = ty + 8 * i;
        Wt[(size_t)(n0 + r) * DM + (k0 + tx)] = (__bf16)tle[tx][r];
    }
}

// ---------------- m97-style GEMM: A bf16 [M][1024] @ Wt bf16 [N][1024]^T
// 128x128 tile, BK=64, global_load_lds staging, 4 waves (2x2), 16x16x32 MFMA.
// mode 0: bf16 out * oscale; mode 1: V store transposed [b,h,d,s]; mode 2: f32 + resid
static __device__ __forceinline__ void gemm_body_bf16(
    const __bf16* __restrict__ A, const __bf16* __restrict__ Wt,
    const float* __restrict__ bias, const float* __restrict__ resid,
    __bf16* __restrict__ Yb, float* __restrict__ Yf,
    int mode, float oscale, int r0, int c0)
{
    __shared__ __attribute__((aligned(16))) __bf16 As[128 * 64];
    __shared__ __attribute__((aligned(16))) __bf16 Bs[128 * 64];
    const int t = threadIdx.x;
    const int w = t >> 6, lane = t & 63;
    const int l15 = lane & 15, lhi = lane >> 4;
    const int wr = w >> 1, wc = w & 1;
    const int lrow = lane >> 3, lcol = (lane & 7) << 3;  // within 8-row/1KB chunk
    const int jb = w * 4;

    const f32x4 fzero = {0.f, 0.f, 0.f, 0.f};
    f32x4 acc[4][4];
#pragma unroll
    for (int m = 0; m < 4; ++m)
#pragma unroll
        for (int n = 0; n < 4; ++n) acc[m][n] = fzero;

    const __bf16* gA = &A[(size_t)(r0 + jb * 8 + lrow) * DM + lcol];
    const __bf16* gB = &Wt[(size_t)(c0 + jb * 8 + lrow) * DM + lcol];

    for (int kt = 0; kt < DM; kt += 64) {
        __syncthreads();
#pragma unroll
        for (int i = 0; i < 4; ++i) {
            gload16(gA + (size_t)i * 8 * DM + kt, &As[(jb + i) * 512]);
            gload16(gB + (size_t)i * 8 * DM + kt, &Bs[(jb + i) * 512]);
        }
        __syncthreads();
#pragma unroll
        for (int kk = 0; kk < 2; ++kk) {
            bf16x8 af[4], bfr[4];
#pragma unroll
            for (int m = 0; m < 4; ++m)
                af[m] = *reinterpret_cast<const bf16x8*>(
                    &As[(wr * 64 + m * 16 + l15) * 64 + kk * 32 + lhi * 8]);
#pragma unroll
            for (int n = 0; n < 4; ++n)
                bfr[n] = *reinterpret_cast<const bf16x8*>(
                    &Bs[(wc * 64 + n * 16 + l15) * 64 + kk * 32 + lhi * 8]);
#pragma unroll
            for (int m = 0; m < 4; ++m)
#pragma unroll
                for (int n = 0; n < 4; ++n)
                    acc[m][n] = mfma16(af[m], bfr[n], acc[m][n]);
        }
    }
#pragma unroll
    for (int m = 0; m < 4; ++m)
#pragma unroll
        for (int n = 0; n < 4; ++n)
#pragma unroll
            for (int r = 0; r < 4; ++r) {
                int grow = r0 + wr * 64 + m * 16 + lhi * 4 + r;
                int gcol = c0 + wc * 64 + n * 16 + l15;
                float val = acc[m][n][r] + bias[gcol];
                if (mode == 0) {
                    Yb[(size_t)grow * DM + gcol] = (__bf16)(val * oscale);
                } else if (mode == 1) {
                    int bb = grow >> 11, ss = grow & (SL - 1);
                    int hh = gcol >> 6, dd = gcol & 63;
                    Yb[(((size_t)(bb * NHEAD + hh)) * 64 + dd) * SL + ss] = (__bf16)val;
                } else {
                    size_t idx = (size_t)grow * DM + gcol;
                    Yf[idx] = val + resid[idx];
                }
            }
}

__global__ __launch_bounds__(256) void qkv_kernel(
    const __bf16* __restrict__ xq, const __bf16* __restrict__ xk, const __bf16* __restrict__ xv,
    const __bf16* __restrict__ WtQ, const __bf16* __restrict__ WtK, const __bf16* __restrict__ WtV,
    const float* __restrict__ bq, const float* __restrict__ bk, const float* __restrict__ bv,
    __bf16* __restrict__ Qp, __bf16* __restrict__ Kp, __bf16* __restrict__ Vt)
{
    const int z = blockIdx.z;
    const __bf16* X = (z == 0) ? xq : (z == 1) ? xk : xv;
    const __bf16* Wt = (z == 0) ? WtQ : (z == 1) ? WtK : WtV;
    const float* bias = (z == 0) ? bq : (z == 1) ? bk : bv;
    __bf16* Yb = (z == 0) ? Qp : (z == 1) ? Kp : Vt;
    int mode = (z == 2) ? 1 : 0;
    float oscale = (z == 0) ? 0.125f : 1.0f;   // fold 1/sqrt(D_K) into Q
    gemm_body_bf16(X, Wt, bias, nullptr, Yb, nullptr, mode, oscale,
                   blockIdx.y * 128, blockIdx.x * 128);
}

__global__ __launch_bounds__(256) void oproj_kernel(
    const __bf16* __restrict__ Cxb, const __bf16* __restrict__ WtO,
    const float* __restrict__ bo, const float* __restrict__ resid,
    float* __restrict__ pre)
{
    gemm_body_bf16(Cxb, WtO, bo, resid, nullptr, pre, 2, 1.0f,
                   blockIdx.y * 128, blockIdx.x * 128);
}

// ---------------- flash attention v4: 8 waves/block, 32 q-rows/wave, 32x32x16
// MFMA, double-buffered swizzled LDS K/V + async reg prefetch, in-reg softmax.
__global__ __launch_bounds__(512, 2) void attn_kernel(
    const __bf16* __restrict__ Qp, const __bf16* __restrict__ Kp,
    const __bf16* __restrict__ Vt, __bf16* __restrict__ Cxb)
{
    __shared__ __attribute__((aligned(16))) __bf16 Kl[2][4096];  // [64 key][64 d] swz
    __shared__ __attribute__((aligned(16))) __bf16 Vl[2][4096];  // [64 d][64 key] swz
    const int t = threadIdx.x;
    const int w = t >> 6, lane = t & 63;
    const int l31 = lane & 31, hi = lane >> 5;

    // XCD swizzle: XCD x owns 4 consecutive bh (K/V 2MB -> L2-resident)
    const int id = blockIdx.x;
    const int logical = (id & 7) * 32 + (id >> 3);
    const int bh = logical >> 3, qs = logical & 7;
    const int b = bh >> 4, h = bh & 15;
    const size_t tokQ = (size_t)b * SL + qs * 256 + w * 32;
    const size_t kbase = (size_t)b * SL;
    const size_t vrow0 = (size_t)bh * 64;

    // staging coords: 512 threads, 1 bf16x8 each for K and V per tile
    const int srow = t >> 3, scol = (t & 7) << 3;
    const __bf16* gK = &Kp[(kbase + srow) * DM + h * 64 + scol];
    const __bf16* gV = &Vt[(vrow0 + srow) * SL + scol];
    const int sidx = ((srow * 128 + scol * 2) ^ ((srow & 7) << 4)) >> 1;

    // Q B-fragments: col=l31 -> q-row, k=d=16*ks+8*hi+j (Q pre-scaled by 1/8)
    bf16x8 bq[4];
#pragma unroll
    for (int ks = 0; ks < 4; ++ks)
        bq[ks] = *reinterpret_cast<const bf16x8*>(
            &Qp[(tokQ + l31) * DM + h * 64 + ks * 16 + hi * 8]);

    f32x16 o0, o1;
#pragma unroll
    for (int r = 0; r < 16; ++r) { o0[r] = 0.f; o1[r] = 0.f; }
    float m_run = -1e30f, l_run = 0.f;

    const int swz = (l31 & 7) << 4;

    // prologue: stage tile 0
    {
        bf16x8 kv = *reinterpret_cast<const bf16x8*>(gK);
        bf16x8 vv = *reinterpret_cast<const bf16x8*>(gV);
        *reinterpret_cast<bf16x8*>(&Kl[0][sidx]) = kv;
        *reinterpret_cast<bf16x8*>(&Vl[0][sidx]) = vv;
    }

    for (int ti = 0; ti < SL / 64; ++ti) {
        const int cb = ti & 1;
        const bool pf = (ti + 1 < SL / 64);
        bf16x8 kvn, vvn;
        if (pf) {   // async-STAGE: issue next-tile loads, consume after compute
            kvn = *reinterpret_cast<const bf16x8*>(gK + (size_t)(ti + 1) * 64 * DM);
            vvn = *reinterpret_cast<const bf16x8*>(gV + (ti + 1) * 64);
        }
        __syncthreads();

        // ---- QK^T (swapped): C[key][q]
        f32x16 c0, c1;
#pragma unroll
        for (int r = 0; r < 16; ++r) { c0[r] = 0.f; c1[r] = 0.f; }
        __builtin_amdgcn_s_setprio(1);
#pragma unroll
        for (int ks = 0; ks < 4; ++ks) {
            int off = ks * 32 + hi * 16;
            bf16x8 ak0 = *reinterpret_cast<const bf16x8*>(&Kl[cb][((l31 * 128 + off) ^ swz) >> 1]);
            bf16x8 ak1 = *reinterpret_cast<const bf16x8*>(&Kl[cb][(((32 + l31) * 128 + off) ^ swz) >> 1]);
            c0 = mfma32(ak0, bq[ks], c0);
            c1 = mfma32(ak1, bq[ks], c1);
        }
        __builtin_amdgcn_s_setprio(0);

        // ---- in-register softmax: lane owns q=l31 for 32 keys (pair lane^32)
        float tm = c0[0];
#pragma unroll
        for (int r = 1; r < 16; ++r) tm = fmaxf(tm, c0[r]);
#pragma unroll
        for (int r = 0; r < 16; ++r) tm = fmaxf(tm, c1[r]);
        tm = fmaxf(tm, __shfl_xor(tm, 32));

        if (__any(tm > m_run + 8.f)) {   // defer-max
            float nm = fmaxf(m_run, tm);
            float sc = __expf(m_run - nm);
            m_run = nm;
            l_run *= sc;
#pragma unroll
            for (int r = 0; r < 16; ++r) {
                float sq = __shfl(sc, (r & 3) + 8 * (r >> 2) + 4 * hi);
                o0[r] *= sq; o1[r] *= sq;
            }
        }

        float rs = 0.f;
#pragma unroll
        for (int r = 0; r < 16; ++r) { c0[r] = __expf(c0[r] - m_run); rs += c0[r]; }
#pragma unroll
        for (int r = 0; r < 16; ++r) { c1[r] = __expf(c1[r] - m_run); rs += c1[r]; }
        rs += __shfl_xor(rs, 32);
        l_run += rs;

        // ---- pack P -> bf16 words, redistribute to PV A-fragments
        unsigned wd0[8], wd1[8];
#pragma unroll
        for (int tt = 0; tt < 4; ++tt)
#pragma unroll
            for (int p = 0; p < 2; ++p) {
                wd0[tt * 2 + p] = packbf(c0[4 * tt + 2 * p], c0[4 * tt + 2 * p + 1]);
                wd1[tt * 2 + p] = packbf(c1[4 * tt + 2 * p], c1[4 * tt + 2 * p + 1]);
            }
        unsigned ua[4][4];
#pragma unroll
        for (int s = 0; s < 4; ++s) {
            int tA = (s & 1) * 2;
#pragma unroll
            for (int p = 0; p < 2; ++p) {
                unsigned A, B;
                if (s < 2) half_swap(wd0[tA * 2 + p], wd0[(tA + 1) * 2 + p], hi, A, B);
                else       half_swap(wd1[tA * 2 + p], wd1[(tA + 1) * 2 + p], hi, A, B);
                ua[s][p] = A; ua[s][2 + p] = B;
            }
        }

        // ---- PV
        __builtin_amdgcn_s_setprio(1);
#pragma unroll
        for (int s = 0; s < 4; ++s) {
            bf16x8 as = *reinterpret_cast<const bf16x8*>(&ua[s][0]);
            bf16x8 vf0 = *reinterpret_cast<const bf16x8*>(
                &Vl[cb][((l31 * 128 + s * 32 + hi * 16) ^ swz) >> 1]);
            bf16x8 vf1 = *reinterpret_cast<const bf16x8*>(
                &Vl[cb][(((32 + l31) * 128 + s * 32 + hi * 16) ^ swz) >> 1]);
            o0 = mfma32(as, vf0, o0);
            o1 = mfma32(as, vf1, o1);
        }
        __builtin_amdgcn_s_setprio(0);

        if (pf) {   // write next tile into the other buffer (safe: all waves
                    // passed this iteration's barrier, so prior reads of cb^1 done)
            *reinterpret_cast<bf16x8*>(&Kl[cb ^ 1][sidx]) = kvn;
            *reinterpret_cast<bf16x8*>(&Vl[cb ^ 1][sidx]) = vvn;
        }
    }

    // ---- normalize + write ctx (bf16)
#pragma unroll
    for (int r = 0; r < 16; ++r) {
        int qq = (r & 3) + 8 * (r >> 2) + 4 * hi;
        float inv = 1.f / __shfl(l_run, qq);
        size_t rowi = (tokQ + qq) * DM + h * 64;
        Cxb[rowi + l31]      = (__bf16)(o0[r] * inv);
        Cxb[rowi + 32 + l31] = (__bf16)(o1[r] * inv);
    }
}

// ---------------- LayerNorm over rows of 1024
__global__ __launch_bounds__(256) void ln_kernel(
    const float* __restrict__ X, const float* __restrict__ gamma,
    const float* __restrict__ beta, float* __restrict__ out)
{
    const int row = blockIdx.x, t = threadIdx.x;
    float4 v = *reinterpret_cast<const float4*>(&X[(size_t)row * DM + t * 4]);
    float s = v.x + v.y + v.z + v.w;
    float s2 = v.x * v.x + v.y * v.y + v.z * v.z + v.w * v.w;
#pragma unroll
    for (int off = 1; off < 64; off <<= 1) {
        s += __shfl_xor(s, off);
        s2 += __shfl_xor(s2, off);
    }
    __shared__ float rs[4], rs2[4];
    const int w = t >> 6;
    if ((t & 63) == 0) { rs[w] = s; rs2[w] = s2; }
    __syncthreads();
    s = rs[0] + rs[1] + rs[2] + rs[3];
    s2 = rs2[0] + rs2[1] + rs2[2] + rs2[3];
    float mean = s * (1.f / DM);
    float var = s2 * (1.f / DM) - mean * mean;
    float rstd = rsqrtf(var + 1e-5f);
    int c = t * 4;
    float4 o;
    o.x = (v.x - mean) * rstd * gamma[c + 0] + beta[c + 0];
    o.y = (v.y - mean) * rstd * gamma[c + 1] + beta[c + 1];
    o.z = (v.z - mean) * rstd * gamma[c + 2] + beta[c + 2];
    o.w = (v.w - mean) * rstd * gamma[c + 3] + beta[c + 3];
    *reinterpret_cast<float4*>(&out[(size_t)row * DM + c]) = o;
}

extern "C" void kernel_launch(void* const* d_in, const int* in_sizes, int n_in,
                              void* d_out, int out_size, void* d_ws, size_t ws_size,
                              hipStream_t stream) {
    (void)in_sizes; (void)n_in; (void)out_size; (void)ws_size;
    const float* q   = (const float*)d_in[0];
    const float* k   = (const float*)d_in[1];
    const float* v   = (const float*)d_in[2];
    const float* Wq  = (const float*)d_in[3];
    const float* bq  = (const float*)d_in[4];
    const float* Wk  = (const float*)d_in[5];
    const float* bk  = (const float*)d_in[6];
    const float* Wv  = (const float*)d_in[7];
    const float* bv  = (const float*)d_in[8];
    const float* Wo  = (const float*)d_in[9];
    const float* bo  = (const float*)d_in[10];
    const float* lng = (const float*)d_in[11];
    const float* lnb = (const float*)d_in[12];

    char* ws = (char*)d_ws;
    const size_t MB = (size_t)1 << 20;
    __bf16* WtQ = (__bf16*)(ws + 0 * MB);
    __bf16* WtK = (__bf16*)(ws + 2 * MB);
    __bf16* WtV = (__bf16*)(ws + 4 * MB);
    __bf16* WtO = (__bf16*)(ws + 6 * MB);
    __bf16* Xbq = (__bf16*)(ws + 8 * MB);    // [4096][1024] bf16
    __bf16* Xbk = (__bf16*)(ws + 16 * MB);
    __bf16* Xbv = (__bf16*)(ws + 24 * MB);
    __bf16* Qp  = (__bf16*)(ws + 32 * MB);   // pre-scaled by 1/8
    __bf16* Kp  = (__bf16*)(ws + 40 * MB);
    __bf16* Vt  = (__bf16*)(ws + 48 * MB);   // [b][h][64][2048]
    __bf16* Cxb = (__bf16*)(ws + 56 * MB);   // ctx bf16 [4096][1024]
    float*  pre = (float*)(ws + 8 * MB);     // reuse Xbq/Xbk (dead after qkv), 16MB
    // total ws footprint: 64 MB

    cast_kernel<<<dim3(2048, 3), 256, 0, stream>>>(q, k, v, Xbq, Xbk, Xbv);
    wt4_kernel<<<dim3(32, 32, 4), dim3(32, 8), 0, stream>>>(
        Wq, Wk, Wv, Wo, WtQ, WtK, WtV, WtO);

    qkv_kernel<<<dim3(8, 32, 3), 256, 0, stream>>>(Xbq, Xbk, Xbv, WtQ, WtK, WtV,
                                                   bq, bk, bv, Qp, Kp, Vt);
    attn_kernel<<<dim3(256), 512, 0, stream>>>(Qp, Kp, Vt, Cxb);
    oproj_kernel<<<dim3(8, 32), 256, 0, stream>>>(Cxb, WtO, bo, q, pre);
    ln_kernel<<<4096, 256, 0, stream>>>(pre, lng, lnb, (float*)d_out);
}